// Round 3
// baseline (201.027 us; speedup 1.0000x reference)
//
#include <hip/hip_runtime.h>
#include <hip/hip_bf16.h>

#define NN   4096
#define FIN  512
#define NH   4
#define DD   64

typedef float f32x4 __attribute__((ext_vector_type(4)));
typedef short s16x8 __attribute__((ext_vector_type(8)));

__device__ __forceinline__ void gld_lds16(const void* g, void* l) {
  __builtin_amdgcn_global_load_lds(
      (const __attribute__((address_space(1))) void*)g,
      (__attribute__((address_space(3))) void*)l, 16, 0, 0);
}

// manual RNE float->bf16
__device__ __forceinline__ short bfbits(float f) {
  union { float f; unsigned u; } v; v.f = f;
  unsigned r = v.u + 0x7FFFu + ((v.u >> 16) & 1u);
  return (short)(r >> 16);
}

// packed pair float->bf16 (hot path) — manual RNE, packed into one int
__device__ __forceinline__ int pkbf(float a, float b) {
  union { float f; unsigned u; } va, vb;
  va.f = a; vb.f = b;
  unsigned ra = (va.u + 0x7FFFu + ((va.u >> 16) & 1u)) >> 16;
  unsigned rb = (vb.u + 0x7FFFu + ((vb.u >> 16) & 1u)) & 0xFFFF0000u;
  return (int)(ra | rb);
}

__device__ __forceinline__ float hexp2(float x) {
#if __has_builtin(__builtin_amdgcn_exp2f)
  return __builtin_amdgcn_exp2f(x);
#else
  return __builtin_exp2f(x);
#endif
}

// ---------------------------------------------------------------------------
// Kernel 1: Wx = X @ W[h]  (bf16 MFMA), store WxT[h][d][n] bf16 (transposed for
// k2's LDS staging), plus s_src/s_dst scaled by log2(e).
// grid 256 = 64 row-tiles x 4 heads, 256 threads (4 waves).
// ---------------------------------------------------------------------------
__global__ __launch_bounds__(256) void gat_k1(
    const float* __restrict__ x, const float* __restrict__ W,
    const float* __restrict__ a,
    short* __restrict__ WxT, float* __restrict__ ssrc, float* __restrict__ sdst)
{
  __shared__ short As[64 * 32];   // [m][k] bf16
  __shared__ short Bs[64 * 40];   // [d][k] bf16, padded stride 40
  __shared__ float Cs[64 * 65];   // [d][n] fp32, padded stride 65

  const int bx = blockIdx.x;
  const int h  = bx >> 6;
  const int r  = bx & 63;
  const int n0 = r * 64;
  const int t  = threadIdx.x;
  const int w  = t >> 6, lane = t & 63;
  const int lm = lane & 15, q = lane >> 4;

  f32x4 acc[4] = {};
  const float* Wh = W + (size_t)h * (FIN * DD);

  for (int ki = 0; ki < FIN / 32; ++ki) {
    const int f0 = ki * 32;
    // stage A: x[n0+row][f0..f0+32) -> As[row][k]
    {
      const int row = t >> 2, fc = (t & 3) * 8;
      const float* xp = x + (size_t)(n0 + row) * FIN + f0 + fc;
      float4 v0 = *(const float4*)xp;
      float4 v1 = *(const float4*)(xp + 4);
      union { short s[8]; int4 v; } u;
      u.s[0] = bfbits(v0.x); u.s[1] = bfbits(v0.y);
      u.s[2] = bfbits(v0.z); u.s[3] = bfbits(v0.w);
      u.s[4] = bfbits(v1.x); u.s[5] = bfbits(v1.y);
      u.s[6] = bfbits(v1.z); u.s[7] = bfbits(v1.w);
      *(int4*)(&As[row * 32 + fc]) = u.v;
    }
    // stage B transposed: W[h][f0+fr][dc..dc+8) -> Bs[d][fr]
    {
      const int fr = t >> 3, dc = (t & 7) * 8;
      const float* wp = Wh + (size_t)(f0 + fr) * DD + dc;
      float4 w0 = *(const float4*)wp;
      float4 w1 = *(const float4*)(wp + 4);
      Bs[(dc + 0) * 40 + fr] = bfbits(w0.x);
      Bs[(dc + 1) * 40 + fr] = bfbits(w0.y);
      Bs[(dc + 2) * 40 + fr] = bfbits(w0.z);
      Bs[(dc + 3) * 40 + fr] = bfbits(w0.w);
      Bs[(dc + 4) * 40 + fr] = bfbits(w1.x);
      Bs[(dc + 5) * 40 + fr] = bfbits(w1.y);
      Bs[(dc + 6) * 40 + fr] = bfbits(w1.z);
      Bs[(dc + 7) * 40 + fr] = bfbits(w1.w);
    }
    __syncthreads();
    s16x8 af = *(const s16x8*)(&As[(w * 16 + lm) * 32 + q * 8]);
#pragma unroll
    for (int c = 0; c < 4; ++c) {
      s16x8 bf = *(const s16x8*)(&Bs[(c * 16 + lm) * 40 + q * 8]);
      acc[c] = __builtin_amdgcn_mfma_f32_16x16x32_bf16(af, bf, acc[c], 0, 0, 0);
    }
    __syncthreads();
  }

  // scatter C to LDS transposed: Cs[d][nloc]  (C layout: col=lm+16c, row=q*4+reg)
#pragma unroll
  for (int c = 0; c < 4; ++c)
#pragma unroll
    for (int g = 0; g < 4; ++g)
      Cs[(c * 16 + lm) * 65 + (w * 16 + q * 4 + g)] = acc[c][g];
  __syncthreads();

  // epilogue 1: WxT[h][d][n0..n0+64) bf16
  {
    const int d = t >> 2, ch = t & 3;
    short tmp[16];
#pragma unroll
    for (int u2 = 0; u2 < 16; ++u2) tmp[u2] = bfbits(Cs[d * 65 + ch * 16 + u2]);
    int4* dst = (int4*)(WxT + (size_t)(h * 64 + d) * NN + n0 + ch * 16);
    dst[0] = *(int4*)(&tmp[0]);
    dst[1] = *(int4*)(&tmp[8]);
  }
  // epilogue 2: s_src / s_dst (scaled by log2 e)
  if (t < 128) {
    const int n = t & 63;
    const int isdst = t >> 6;
    const float* av = a + h * 128 + isdst * 64;
    float s = 0.f;
#pragma unroll 8
    for (int d = 0; d < 64; ++d) s = fmaf(Cs[d * 65 + n], av[d], s);
    const float LOG2E = 1.4426950408889634f;
    (isdst ? sdst : ssrc)[h * NN + n0 + n] = s * LOG2E;
  }
}

// ---------------------------------------------------------------------------
// Kernel 2: out[i][h*64+d] = relu( (sum_j p_ij * Wx[j][d]) / (sum_j p_ij) + bias )
// p_ij = exp(leaky(s_src_i + s_dst_j)) * adj_ij, computed on the fly in exp2 form.
// grid 256 = h*64 + rowtile. 512 threads = 8 waves: sub=w&3 row-subtile,
// kc=w>>2 K-chunk (j half).
// ---------------------------------------------------------------------------
__global__ __launch_bounds__(512) void gat_k2(
    const int* __restrict__ adj, const short* __restrict__ WxT,
    const float* __restrict__ ssrc, const float* __restrict__ sdst,
    const float* __restrict__ bias, float* __restrict__ out)
{
  __shared__ short VT[2][64 * 32];   // [kc] [d*32 + j] bf16 V^T tile
  __shared__ float MRG[4][16 * 64];  // merge buffer for K-chunk reduction
  __shared__ float Lbuf[4][16];
  __shared__ float Lfin[4][16];

  const int bx = blockIdx.x;
  const int h  = bx >> 6;
  const int r  = bx & 63;
  const int t  = threadIdx.x;
  const int w  = t >> 6, lane = t & 63;
  const int sub = w & 3, kc = w >> 2;
  const int lm = lane & 15, q = lane >> 4;

  const int i = r * 64 + sub * 16 + lm;                 // P-row this lane generates
  const float src_i = ssrc[h * NN + i] - 1000.0f;       // fold mask bias in

  const short one = 0x3F80;                              // bf16 1.0
  s16x8 bones = {};
  if (lm == 0) {
    bones[0] = one; bones[1] = one; bones[2] = one; bones[3] = one;
    bones[4] = one; bones[5] = one; bones[6] = one; bones[7] = one;
  }

  f32x4 acc[4] = {};
  f32x4 accl = {};

  // staging assignment for this wave (stages its own chunk's quarter)
  const int sd  = sub * 16 + (lane >> 2);
  const int sjc = (lane & 3) * 8;
  const short* gstage = WxT + (size_t)(h * 64 + sd) * NN + kc * 2048 + sjc;
  short* lds_base = &VT[kc][sub * 512];

  const int jb0 = kc * 2048;
  // NOTE: int4/float4 pointers — one K-step (32 columns) = 8 vector elements.
  const int4*   ap = (const int4*)(adj + (size_t)i * NN + jb0 + q * 8);
  const float4* sp = (const float4*)(sdst + h * NN + jb0 + q * 8);

  int4   pa0 = ap[0], pa1 = ap[1];
  float4 ps0 = sp[0], ps1 = sp[1];

  for (int ks = 0; ks < 64; ++ks) {
    gld_lds16(gstage + ks * 32, lds_base);

    // generate 8 p values from prefetched adj/sdst (no LDS dependence)
    float p[8];
#define PGEN(dv, av, idx)                                              \
    { float tp = src_i + (dv);                                         \
      float u  = fmaxf(tp, fmaf(tp, 0.2f, -800.0f));                   \
      u = fmaf((float)(av), 1000.0f, u);                               \
      p[idx] = hexp2(u); }
    PGEN(ps0.x, pa0.x, 0) PGEN(ps0.y, pa0.y, 1)
    PGEN(ps0.z, pa0.z, 2) PGEN(ps0.w, pa0.w, 3)
    PGEN(ps1.x, pa1.x, 4) PGEN(ps1.y, pa1.y, 5)
    PGEN(ps1.z, pa1.z, 6) PGEN(ps1.w, pa1.w, 7)
#undef PGEN
    union { int i4[4]; s16x8 v; } af;
    af.i4[0] = pkbf(p[0], p[1]);
    af.i4[1] = pkbf(p[2], p[3]);
    af.i4[2] = pkbf(p[4], p[5]);
    af.i4[3] = pkbf(p[6], p[7]);

    // prefetch next step's adj / sdst before the barrier
    // (stride per K-step: 32 elements = 8 int4/float4)
    if (ks < 63) {
      pa0 = ap[(ks + 1) * 8]; pa1 = ap[(ks + 1) * 8 + 1];
      ps0 = sp[(ks + 1) * 8]; ps1 = sp[(ks + 1) * 8 + 1];
    }

    __syncthreads();   // VT staged (vmcnt drain) + prefetches landed

#pragma unroll
    for (int c = 0; c < 4; ++c) {
      s16x8 bf = *(const s16x8*)(&VT[kc][(c * 16 + lm) * 32 + q * 8]);
      acc[c] = __builtin_amdgcn_mfma_f32_16x16x32_bf16(af.v, bf, acc[c], 0, 0, 0);
    }
    accl = __builtin_amdgcn_mfma_f32_16x16x32_bf16(af.v, bones, accl, 0, 0, 0);

    __syncthreads();   // protect VT before next stage
  }

  // merge the two K-chunks (waves kc==1 -> LDS, kc==0 adds)
  if (kc == 1) {
#pragma unroll
    for (int c = 0; c < 4; ++c)
#pragma unroll
      for (int g = 0; g < 4; ++g)
        MRG[sub][(q * 4 + g) * 64 + c * 16 + lm] = acc[c][g];
    if (lm == 0) {
#pragma unroll
      for (int g = 0; g < 4; ++g) Lbuf[sub][q * 4 + g] = accl[g];
    }
  }
  __syncthreads();
  if (kc == 0) {
#pragma unroll
    for (int c = 0; c < 4; ++c)
#pragma unroll
      for (int g = 0; g < 4; ++g)
        acc[c][g] += MRG[sub][(q * 4 + g) * 64 + c * 16 + lm];
    if (lm == 0) {
#pragma unroll
      for (int g = 0; g < 4; ++g) Lfin[sub][q * 4 + g] = accl[g] + Lbuf[sub][q * 4 + g];
    }
  }
  __syncthreads();
  if (kc == 0) {
#pragma unroll
    for (int g = 0; g < 4; ++g) {
      const float l = Lfin[sub][q * 4 + g];
      const float inv = 1.0f / l;
      const int row = r * 64 + sub * 16 + q * 4 + g;
#pragma unroll
      for (int c = 0; c < 4; ++c) {
        const int col = h * 64 + c * 16 + lm;
        float o = fmaf(acc[c][g], inv, bias[col]);
        out[(size_t)row * 256 + col] = fmaxf(o, 0.0f);
      }
    }
  }
}

// ---------------------------------------------------------------------------
extern "C" void kernel_launch(void* const* d_in, const int* in_sizes, int n_in,
                              void* d_out, int out_size, void* d_ws, size_t ws_size,
                              hipStream_t stream) {
  const float* x    = (const float*)d_in[0];
  const int*   adj  = (const int*)d_in[1];
  const float* W    = (const float*)d_in[2];
  const float* a    = (const float*)d_in[3];
  const float* bias = (const float*)d_in[4];
  float* out = (float*)d_out;

  short* WxT  = (short*)d_ws;                                  // 2 MB bf16
  float* ssrc = (float*)((char*)d_ws + (size_t)NH * DD * NN * 2);
  float* sdst = ssrc + NH * NN;

  gat_k1<<<256, 256, 0, stream>>>(x, W, a, WxT, ssrc, sdst);
  gat_k2<<<256, 512, 0, stream>>>(adj, WxT, ssrc, sdst, bias, out);
}

// Round 4
// 155.984 us; speedup vs baseline: 1.2888x; 1.2888x over previous
//
#include <hip/hip_runtime.h>
#include <hip/hip_bf16.h>

#define NN   4096
#define FIN  512
#define NH   4
#define DD   64

typedef float f32x4 __attribute__((ext_vector_type(4)));
typedef short s16x8 __attribute__((ext_vector_type(8)));

__device__ __forceinline__ void gld_lds16(const void* g, void* l) {
  __builtin_amdgcn_global_load_lds(
      (const __attribute__((address_space(1))) void*)g,
      (__attribute__((address_space(3))) void*)l, 16, 0, 0);
}

// manual RNE float->bf16
__device__ __forceinline__ short bfbits(float f) {
  union { float f; unsigned u; } v; v.f = f;
  unsigned r = v.u + 0x7FFFu + ((v.u >> 16) & 1u);
  return (short)(r >> 16);
}

// packed pair float->bf16
__device__ __forceinline__ int pkbf(float a, float b) {
  union { float f; unsigned u; } va, vb;
  va.f = a; vb.f = b;
  unsigned ra = (va.u + 0x7FFFu + ((va.u >> 16) & 1u)) >> 16;
  unsigned rb = (vb.u + 0x7FFFu + ((vb.u >> 16) & 1u)) & 0xFFFF0000u;
  return (int)(ra | rb);
}

__device__ __forceinline__ float hexp2(float x) {
#if __has_builtin(__builtin_amdgcn_exp2f)
  return __builtin_amdgcn_exp2f(x);
#else
  return __builtin_exp2f(x);
#endif
}

// ---------------------------------------------------------------------------
// Kernel 1: Wx = X @ W[h] (bf16 MFMA). grid 256 = (h, 64-row tile), 512 thr.
// K staged in 4 chunks of 128 (big tiles, 8 barriers total). Padded LDS
// strides (136 shorts = balanced banks). Outputs WxT[h][d][n] bf16 + scaled
// s_src/s_dst.
// ---------------------------------------------------------------------------
__global__ __launch_bounds__(512) void gat_k1(
    const float* __restrict__ x, const float* __restrict__ W,
    const float* __restrict__ a,
    short* __restrict__ WxT, float* __restrict__ ssrc, float* __restrict__ sdst)
{
  __shared__ __align__(16) char sm[34816];
  short* As = (short*)sm;                 // [64 rows][136]  (128 used)
  short* Bs = (short*)(sm + 17408);       // [64 d][136]
  float* Cs = (float*)sm;                 // overlay: [64 d][65] after MFMA

  const int bx = blockIdx.x;
  const int h  = bx >> 6;
  const int r  = bx & 63;
  const int n0 = r * 64;
  const int t  = threadIdx.x;
  const int w  = t >> 6, lane = t & 63;
  const int lm = lane & 15, q = lane >> 4;
  const int rs = w & 3, cs = w >> 2;

  f32x4 acc[2] = {};
  const float* Wh = W + (size_t)h * (FIN * DD);

  for (int kq = 0; kq < 4; ++kq) {
    // stage A: x[n0+row][kq*128 + fl .. +16)
    {
      const int row = t >> 3, fl = (t & 7) * 16;
      const float* xp = x + (size_t)(n0 + row) * FIN + kq * 128 + fl;
      float4 v0 = ((const float4*)xp)[0];
      float4 v1 = ((const float4*)xp)[1];
      float4 v2 = ((const float4*)xp)[2];
      float4 v3 = ((const float4*)xp)[3];
      union { short s[8]; int4 v; } u0, u1;
      u0.s[0]=bfbits(v0.x); u0.s[1]=bfbits(v0.y); u0.s[2]=bfbits(v0.z); u0.s[3]=bfbits(v0.w);
      u0.s[4]=bfbits(v1.x); u0.s[5]=bfbits(v1.y); u0.s[6]=bfbits(v1.z); u0.s[7]=bfbits(v1.w);
      u1.s[0]=bfbits(v2.x); u1.s[1]=bfbits(v2.y); u1.s[2]=bfbits(v2.z); u1.s[3]=bfbits(v2.w);
      u1.s[4]=bfbits(v3.x); u1.s[5]=bfbits(v3.y); u1.s[6]=bfbits(v3.z); u1.s[7]=bfbits(v3.w);
      *(int4*)(As + row * 136 + fl)     = u0.v;
      *(int4*)(As + row * 136 + fl + 8) = u1.v;
    }
    // stage B transposed: W[h][kq*128+fl][dc..dc+16) -> Bs[d][fl]
    {
      const int fl = t >> 2, dc = (t & 3) * 16;
      const float* wp = Wh + (size_t)(kq * 128 + fl) * DD + dc;
      float4 w0 = ((const float4*)wp)[0];
      float4 w1 = ((const float4*)wp)[1];
      float4 w2 = ((const float4*)wp)[2];
      float4 w3 = ((const float4*)wp)[3];
      Bs[(dc+ 0)*136+fl]=bfbits(w0.x); Bs[(dc+ 1)*136+fl]=bfbits(w0.y);
      Bs[(dc+ 2)*136+fl]=bfbits(w0.z); Bs[(dc+ 3)*136+fl]=bfbits(w0.w);
      Bs[(dc+ 4)*136+fl]=bfbits(w1.x); Bs[(dc+ 5)*136+fl]=bfbits(w1.y);
      Bs[(dc+ 6)*136+fl]=bfbits(w1.z); Bs[(dc+ 7)*136+fl]=bfbits(w1.w);
      Bs[(dc+ 8)*136+fl]=bfbits(w2.x); Bs[(dc+ 9)*136+fl]=bfbits(w2.y);
      Bs[(dc+10)*136+fl]=bfbits(w2.z); Bs[(dc+11)*136+fl]=bfbits(w2.w);
      Bs[(dc+12)*136+fl]=bfbits(w3.x); Bs[(dc+13)*136+fl]=bfbits(w3.y);
      Bs[(dc+14)*136+fl]=bfbits(w3.z); Bs[(dc+15)*136+fl]=bfbits(w3.w);
    }
    __syncthreads();
#pragma unroll
    for (int s = 0; s < 4; ++s) {
      s16x8 af = *(const s16x8*)(As + (rs * 16 + lm) * 136 + s * 32 + q * 8);
#pragma unroll
      for (int c = 0; c < 2; ++c) {
        s16x8 bf = *(const s16x8*)(Bs + (cs * 32 + c * 16 + lm) * 136 + s * 32 + q * 8);
        acc[c] = __builtin_amdgcn_mfma_f32_16x16x32_bf16(af, bf, acc[c], 0, 0, 0);
      }
    }
    __syncthreads();
  }

  // scatter C transposed into Cs[d][n] (overlays As; barrier above protects)
#pragma unroll
  for (int c = 0; c < 2; ++c)
#pragma unroll
    for (int g = 0; g < 4; ++g)
      Cs[(cs * 32 + c * 16 + lm) * 65 + (rs * 16 + q * 4 + g)] = acc[c][g];
  __syncthreads();

  // epilogue 1: WxT[h][d][n0..n0+64) bf16
  {
    const int d = t >> 3, nc = (t & 7) * 8;
    union { short s[8]; int4 v; } u;
#pragma unroll
    for (int e = 0; e < 8; ++e) u.s[e] = bfbits(Cs[d * 65 + nc + e]);
    *(int4*)(WxT + (size_t)(h * 64 + d) * NN + n0 + nc) = u.v;
  }
  // epilogue 2: s_src / s_dst (scaled by log2 e)
  if (t < 128) {
    const int n = t & 63;
    const int isdst = t >> 6;
    const float* av = a + h * 128 + isdst * 64;
    float s = 0.f;
#pragma unroll 8
    for (int d = 0; d < 64; ++d) s = fmaf(Cs[d * 65 + n], av[d], s);
    const float LOG2E = 1.4426950408889634f;
    (isdst ? sdst : ssrc)[h * NN + n0 + n] = s * LOG2E;
  }
}

// ---------------------------------------------------------------------------
// Kernel 2: flash-style masked-softmax @ V. grid 256 = (h, 64-row tile),
// 512 thr = 8 waves: ms (2 row-halves of 32) x kc (4 j-quarters of 64).
// j-blocks of 256 cols, double-buffered V in LDS, ONE barrier per j-block,
// adj/sdst register-prefetched one block ahead.
// ---------------------------------------------------------------------------
__global__ __launch_bounds__(512) void gat_k2(
    const int* __restrict__ adj, const short* __restrict__ WxT,
    const float* __restrict__ ssrc, const float* __restrict__ sdst,
    const float* __restrict__ bias, float* __restrict__ out)
{
  __shared__ __align__(16) char sm[65536];
  short* VT  = (short*)sm;                  // 2 bufs x 8 tiles x [64 d][32 j]
  float* MRG = (float*)sm;                  // overlay after loop: [3][64][68]
  float* Lm  = (float*)(sm + 52224);        // overlay: [4][64]

  const int bx = blockIdx.x;
  const int h  = bx >> 6;
  const int r  = bx & 63;
  const int t  = threadIdx.x;
  const int w  = t >> 6, lane = t & 63;
  const int ms = w >> 2, kc = w & 3;
  const int lm = lane & 15, q = lane >> 4;

  const int i0 = r * 64 + ms * 32 + lm;
  const int i1 = i0 + 16;
  const float src0 = ssrc[h * NN + i0] - 1000.0f;
  const float src1 = ssrc[h * NN + i1] - 1000.0f;

  const short one = 0x3F80;
  s16x8 bones = {};
  if (lm == 0) {
    bones[0]=one; bones[1]=one; bones[2]=one; bones[3]=one;
    bones[4]=one; bones[5]=one; bones[6]=one; bones[7]=one;
  }

  f32x4 acc[2][4] = {};
  f32x4 accl[2] = {};

  // V staging: wave w stages step-tile w (4 KB) of each j-block via 4 gld.
  // tile layout: [d][32 j] (64 B rows); lane l -> d = k*16 + l/4, jc = (l&3)*8
  const short* gstage = WxT + (size_t)(h * 64 + (lane >> 2)) * NN
                        + w * 32 + (lane & 3) * 8;

  // adj / sdst register prefetch (double-buffered)
  int4   pa[2][8];
  float4 ps[2][4];
  const int jq = kc * 64 + q * 8;

#define LOAD_REGS(set, jb2)                                                   \
  {                                                                           \
    _Pragma("unroll")                                                         \
    for (int s = 0; s < 2; ++s) {                                             \
      const int j = (jb2) * 256 + jq + s * 32;                                \
      const int4* a0 = (const int4*)(adj + (size_t)i0 * NN + j);              \
      const int4* a1 = (const int4*)(adj + (size_t)i1 * NN + j);              \
      pa[set][s*4+0] = a0[0]; pa[set][s*4+1] = a0[1];                         \
      pa[set][s*4+2] = a1[0]; pa[set][s*4+3] = a1[1];                         \
      const float4* sd = (const float4*)(sdst + h * NN + j);                  \
      ps[set][s*2+0] = sd[0]; ps[set][s*2+1] = sd[1];                         \
    }                                                                         \
  }

  // prologue: stage jb=0
#pragma unroll
  for (int k = 0; k < 4; ++k)
    gld_lds16(gstage + (size_t)(k * 16) * NN, VT + w * 2048 + k * 512);
  LOAD_REGS(0, 0)
  __syncthreads();

#pragma unroll
  for (int jb = 0; jb < 16; ++jb) {
    const int cur = jb & 1, nxt = cur ^ 1;
    if (jb < 15) {
#pragma unroll
      for (int k = 0; k < 4; ++k)
        gld_lds16(gstage + (size_t)(k * 16) * NN + (jb + 1) * 256,
                  VT + nxt * 16384 + w * 2048 + k * 512);
      LOAD_REGS(nxt, jb + 1)
    }

    const short* Vc = VT + cur * 16384 + kc * 4096;  // this wave's 2 step-tiles
#pragma unroll
    for (int s = 0; s < 2; ++s) {
      s16x8 bf[4];
#pragma unroll
      for (int c = 0; c < 4; ++c)
        bf[c] = *(const s16x8*)(Vc + s * 2048 + (c * 16 + lm) * 32 + q * 8);
#pragma unroll
      for (int rf = 0; rf < 2; ++rf) {
        const float src_i = rf ? src1 : src0;
        const int4 A0 = pa[cur][s * 4 + rf * 2];
        const int4 A1 = pa[cur][s * 4 + rf * 2 + 1];
        const float4 S0 = ps[cur][s * 2];
        const float4 S1 = ps[cur][s * 2 + 1];
        float p[8];
#define PGEN(dv, av, idx)                                                     \
        { float tp = src_i + (dv);                                            \
          float u  = fmaxf(tp, fmaf(tp, 0.2f, -800.0f));                      \
          u = fmaf((float)(av), 1000.0f, u);                                  \
          p[idx] = hexp2(u); }
        PGEN(S0.x, A0.x, 0) PGEN(S0.y, A0.y, 1)
        PGEN(S0.z, A0.z, 2) PGEN(S0.w, A0.w, 3)
        PGEN(S1.x, A1.x, 4) PGEN(S1.y, A1.y, 5)
        PGEN(S1.z, A1.z, 6) PGEN(S1.w, A1.w, 7)
#undef PGEN
        union { int i4[4]; s16x8 v; } af;
        af.i4[0] = pkbf(p[0], p[1]);
        af.i4[1] = pkbf(p[2], p[3]);
        af.i4[2] = pkbf(p[4], p[5]);
        af.i4[3] = pkbf(p[6], p[7]);
#pragma unroll
        for (int c = 0; c < 4; ++c)
          acc[rf][c] = __builtin_amdgcn_mfma_f32_16x16x32_bf16(af.v, bf[c], acc[rf][c], 0, 0, 0);
        accl[rf] = __builtin_amdgcn_mfma_f32_16x16x32_bf16(af.v, bones, accl[rf], 0, 0, 0);
      }
    }
    __syncthreads();  // VT[nxt] staged + all reads of VT[cur] done
  }
#undef LOAD_REGS

  // ---- merge (LDS overlays VT; loop's last barrier protects) ----
  if (lm == 0) {
#pragma unroll
    for (int rf = 0; rf < 2; ++rf)
#pragma unroll
      for (int g = 0; g < 4; ++g)
        Lm[kc * 64 + ms * 32 + rf * 16 + q * 4 + g] = accl[rf][g];
  }
  if (kc != 0) {
#pragma unroll
    for (int rf = 0; rf < 2; ++rf)
#pragma unroll
      for (int c = 0; c < 4; ++c)
#pragma unroll
        for (int g = 0; g < 4; ++g)
          MRG[((kc - 1) * 64 + ms * 32 + rf * 16 + q * 4 + g) * 68 + c * 16 + lm] = acc[rf][c][g];
  }
  __syncthreads();
  if (kc == 0) {
#pragma unroll
    for (int rf = 0; rf < 2; ++rf) {
#pragma unroll
      for (int g = 0; g < 4; ++g) {
        const int row = ms * 32 + rf * 16 + q * 4 + g;
        float l = Lm[row] + Lm[64 + row] + Lm[128 + row] + Lm[192 + row];
        const float inv = 1.0f / l;
        const int grow = r * 64 + row;
#pragma unroll
        for (int c = 0; c < 4; ++c) {
          const int col = c * 16 + lm;
          float v = acc[rf][c][g]
                  + MRG[(row) * 68 + col]
                  + MRG[(64 + row) * 68 + col]
                  + MRG[(128 + row) * 68 + col];
          float o = fmaf(v, inv, bias[h * 64 + col]);
          out[(size_t)grow * 256 + h * 64 + col] = fmaxf(o, 0.0f);
        }
      }
    }
  }
}

// ---------------------------------------------------------------------------
extern "C" void kernel_launch(void* const* d_in, const int* in_sizes, int n_in,
                              void* d_out, int out_size, void* d_ws, size_t ws_size,
                              hipStream_t stream) {
  const float* x    = (const float*)d_in[0];
  const int*   adj  = (const int*)d_in[1];
  const float* W    = (const float*)d_in[2];
  const float* a    = (const float*)d_in[3];
  const float* bias = (const float*)d_in[4];
  float* out = (float*)d_out;

  short* WxT  = (short*)d_ws;                                  // 2 MB bf16
  float* ssrc = (float*)((char*)d_ws + (size_t)NH * DD * NN * 2);
  float* sdst = ssrc + NH * NN;

  gat_k1<<<256, 512, 0, stream>>>(x, W, a, WxT, ssrc, sdst);
  gat_k2<<<256, 512, 0, stream>>>(adj, WxT, ssrc, sdst, bias, out);
}